// Round 5
// baseline (160.275 us; speedup 1.0000x reference)
//
#include <hip/hip_runtime.h>
#include <hip/hip_bf16.h>
#include <cstdint>

#define DIM   1024
#define HEADS 16
#define BB    32
#define NN    2048
#define DH    64

constexpr float SCALE = 0.03125f;  // 1/sqrt(1024)
constexpr float LN_EPS = 1e-5f;

typedef __attribute__((ext_vector_type(8))) short short8v;
typedef __attribute__((ext_vector_type(4))) float f32x4;

__device__ __forceinline__ short f2bf(float f) {
  union { __hip_bfloat16 h; short s; } u;
  u.h = __float2bfloat16(f);
  return u.s;
}
__device__ __forceinline__ short8v pack8(float4 a, float4 b) {
  short8v v;
  v[0] = f2bf(a.x); v[1] = f2bf(a.y); v[2] = f2bf(a.z); v[3] = f2bf(a.w);
  v[4] = f2bf(b.x); v[5] = f2bf(b.y); v[6] = f2bf(b.z); v[7] = f2bf(b.w);
  return v;
}
__device__ __forceinline__ void fma4(float4& a, float s, float4 x) {
  a.x += s * x.x; a.y += s * x.y; a.z += s * x.z; a.w += s * x.w;
}

// ---------------- helpers ----------------
__device__ __forceinline__ float block_sum256(float v, volatile float* red) {
  #pragma unroll
  for (int off = 32; off; off >>= 1) v += __shfl_xor(v, off);
  __syncthreads();
  if ((threadIdx.x & 63) == 0) red[threadIdx.x >> 6] = v;
  __syncthreads();
  return red[0] + red[1] + red[2] + red[3];
}

// ---------------- K0: compact unmasked indices per batch ----------------
__global__ void k_index(const int* __restrict__ mask, int* __restrict__ idx,
                        int* __restrict__ cnt) {
  int b = blockIdx.x;                          // grid 32
  int tid = threadIdx.x;
  const int* mb = mask + b * NN;
  int base = tid * 8;
  int loc[8], c = 0;
  #pragma unroll
  for (int i = 0; i < 8; ++i) { loc[i] = mb[base + i]; c += (loc[i] != 0); }
  int pre = c;
  #pragma unroll
  for (int off = 1; off < 64; off <<= 1) {
    int y = __shfl_up(pre, off);
    if ((tid & 63) >= off) pre += y;
  }
  __shared__ int wsum[4];
  if ((tid & 63) == 63) wsum[tid >> 6] = pre;
  __syncthreads();
  int wo = 0;
  for (int wv = 0; wv < (tid >> 6); ++wv) wo += wsum[wv];
  int pos = wo + pre - c;                      // exclusive prefix
  int* ib = idx + b * NN;
  #pragma unroll
  for (int i = 0; i < 8; ++i) if (loc[i]) ib[pos++] = base + i;
  if (tid == 255) cnt[b] = wo + pre;
}

// ---------------- K1+K2 merged: per-head Qp in LDS, then qk row; qb ----------------
// grid 64 = 16 h x 4 cblk
__global__ void k_qkp(const float* __restrict__ S, const float* __restrict__ Wq,
                      const float* __restrict__ bq, const float* __restrict__ Wk,
                      const float* __restrict__ bk, float* __restrict__ qk,
                      float* __restrict__ qb) {
  int bi = blockIdx.x;
  int h = bi >> 2, cblk = bi & 3;
  int tid = threadIdx.x;
  __shared__ float qpl[DH];
  int r = tid >> 2, j = tid & 3;               // 4 threads per Wq row
  int d = h * DH + r;
  const float* wr = Wq + (size_t)d * DIM + j * 256;
  const float* sp = S + j * 256;
  float a = 0.f;
  #pragma unroll 8
  for (int k = 0; k < 64; ++k) {
    float4 av = *(const float4*)(wr + k * 4);
    float4 sv = *(const float4*)(sp + k * 4);
    a += av.x * sv.x + av.y * sv.y + av.z * sv.z + av.w * sv.w;
  }
  a += __shfl_xor(a, 1);
  a += __shfl_xor(a, 2);
  if (j == 0) qpl[r] = a + bq[d];
  __syncthreads();
  if (cblk == 0 && tid < 64) {                 // qb[h] = Qp[h,:] . bk[h,:]
    float v = qpl[tid] * bk[h * DH + tid];
    #pragma unroll
    for (int off = 32; off; off >>= 1) v += __shfl_xor(v, off);
    if (tid == 0) qb[h] = v;
  }
  int c = cblk * 256 + tid;
  float acc = 0.f;
  #pragma unroll 8
  for (int d0 = 0; d0 < DH; ++d0)
    acc += qpl[d0] * Wk[(size_t)(h * DH + d0) * DIM + c];
  qk[h * DIM + c] = acc;
}

// ---------------- K3 v5: MFMA scores over COMPACT rows, tiles of 64 ----------------
// grid 512 = 32 b x 16 tg; P[b][h][slot] layout (coalesced softmax reads)
__global__ __launch_bounds__(256) void k_scores5(const float* __restrict__ X,
                                                 const float* __restrict__ qk,
                                                 const int* __restrict__ idx,
                                                 const int* __restrict__ cnt,
                                                 float* __restrict__ P) {
  int b  = blockIdx.x >> 4;
  int tg = blockIdx.x & 15;
  int count = cnt[b];
  int ntiles = (count + 63) >> 6;
  if (ntiles == 0) return;
  __shared__ short qlds[HEADS * 1024];        // 32 KB bf16, XOR-swizzled slots
  int tid = threadIdx.x;
  for (int i = tid; i < HEADS * 128; i += 256) {
    int h = i >> 7, slot = i & 127;
    const float4* qg = (const float4*)(qk + (size_t)h * DIM) + slot * 2;
    float4 f0 = qg[0], f1 = qg[1];
    int ds = slot ^ (h & 7);
    *(short8v*)(qlds + h * 1024 + ds * 8) = pack8(f0, f1);
  }
  __syncthreads();
  int wv = tid >> 6, lane = tid & 63;
  int r16 = lane & 15, kg = lane >> 4;
  const short* qrow = qlds + r16 * 1024;
  int hx = r16 & 7;
  const int* ib = idx + b * NN;

  for (int t = tg; t < ntiles; t += 16) {
    int tilebase = t * 64 + wv * 16;
    int s0 = tilebase + r16;
    int c0 = s0 < count ? s0 : count - 1;
    int i0 = ib[c0];
    const float* x0 = X + ((size_t)b * NN + i0) * DIM + kg * 8;
    f32x4 accA = {0.f, 0.f, 0.f, 0.f}, accB = {0.f, 0.f, 0.f, 0.f};
    #pragma unroll 4
    for (int k0 = 0; k0 < DIM; k0 += 64) {
      float4 a00 = *(const float4*)(x0 + k0);
      float4 a01 = *(const float4*)(x0 + k0 + 4);
      float4 a10 = *(const float4*)(x0 + k0 + 32);
      float4 a11 = *(const float4*)(x0 + k0 + 36);
      short8v b0 = *(const short8v*)(qrow + ((((k0 >> 3) + kg) ^ hx) << 3));
      short8v b1 = *(const short8v*)(qrow + ((((k0 >> 3) + 4 + kg) ^ hx) << 3));
      accA = __builtin_amdgcn_mfma_f32_16x16x32_bf16(pack8(a00, a01), b0, accA, 0, 0, 0);
      accB = __builtin_amdgcn_mfma_f32_16x16x32_bf16(pack8(a10, a11), b1, accB, 0, 0, 0);
    }
    f32x4 acc = accA + accB;
    // D: col(=r16) is head, row(=kg*4+j) is slot within the 16
    float* pb = P + ((size_t)b * HEADS + r16) * NN;
    #pragma unroll
    for (int j = 0; j < 4; ++j) {
      int os = tilebase + kg * 4 + j;
      if (os < count) pb[os] = acc[j];
    }
  }
}

// ---------------- K4: bias + scale + softmax; P[b][h][n] in, w [b][slot][h] out ----------------
__global__ void k_softmax4(const float* __restrict__ P, const float* __restrict__ qb,
                           const int* __restrict__ cnt, float* __restrict__ w,
                           float* __restrict__ lsum) {
  int b = blockIdx.x >> 4, h = blockIdx.x & 15;   // grid 512
  int tid = threadIdx.x;
  int count = cnt[b];
  const float* p0 = P + ((size_t)b * HEADS + h) * NN;
  float qbh = qb[h];
  __shared__ float red[4];
  float s[8]; int vld[8];
  float mx = -3e38f;
  #pragma unroll
  for (int i = 0; i < 8; ++i) {
    int n = tid + i * 256;
    vld[i] = n < count;
    s[i] = vld[i] ? (p0[n] + qbh) * SCALE : 0.f;
    if (vld[i]) mx = fmaxf(mx, s[i]);
  }
  #pragma unroll
  for (int off = 32; off; off >>= 1) mx = fmaxf(mx, __shfl_xor(mx, off));
  if ((tid & 63) == 0) red[tid >> 6] = mx;
  __syncthreads();
  mx = fmaxf(fmaxf(red[0], red[1]), fmaxf(red[2], red[3]));
  float sum = 0.f;
  #pragma unroll
  for (int i = 0; i < 8; ++i) {
    float e = vld[i] ? __expf(s[i] - mx) : 0.f;
    s[i] = e;
    sum += e;
  }
  #pragma unroll
  for (int off = 32; off; off >>= 1) sum += __shfl_xor(sum, off);
  __syncthreads();
  if ((tid & 63) == 0) red[tid >> 6] = sum;
  __syncthreads();
  sum = red[0] + red[1] + red[2] + red[3];
  float inv = sum > 0.f ? 1.f / sum : 0.f;
  float* wb = w + (size_t)b * NN * HEADS + h;
  #pragma unroll
  for (int i = 0; i < 8; ++i) {
    int n = tid + i * 256;
    if (vld[i]) wb[(size_t)n * HEADS] = s[i] * inv;
  }
  if (tid == 0) lsum[b * HEADS + h] = sum > 0.f ? 1.f : 0.f;
}

// ---------------- K5 v3: Z partials over compact rows ----------------
__global__ __launch_bounds__(256) void k_z3(const float* __restrict__ X,
                                            const float* __restrict__ w,
                                            const int* __restrict__ idx,
                                            const int* __restrict__ cnt,
                                            float* __restrict__ Zp, int nchunk) {
  int nc = blockIdx.x % nchunk;
  int b  = blockIdx.x / nchunk;
  int count = cnt[b];
  int NCc = (count + nchunk - 1) / nchunk;
  int start = nc * NCc;
  int end = start + NCc; if (end > count) end = count;
  int c4 = threadIdx.x;
  const float* Xb = X + (size_t)b * NN * DIM;
  const float* wp = w + ((size_t)b * NN) * HEADS;
  const int* ib = idx + b * NN;
  float4 acc[HEADS];
  #pragma unroll
  for (int h = 0; h < HEADS; ++h) acc[h] = make_float4(0.f, 0.f, 0.f, 0.f);
  #pragma unroll 2
  for (int slot = start; slot < end; ++slot) {
    int n = ib[slot];
    float4 x4 = *(const float4*)(Xb + (size_t)n * DIM + c4 * 4);
    const float4* wn = (const float4*)(wp + (size_t)slot * HEADS);  // uniform
    float4 w0 = wn[0], w1 = wn[1], w2 = wn[2], w3 = wn[3];
    fma4(acc[0],  w0.x, x4); fma4(acc[1],  w0.y, x4);
    fma4(acc[2],  w0.z, x4); fma4(acc[3],  w0.w, x4);
    fma4(acc[4],  w1.x, x4); fma4(acc[5],  w1.y, x4);
    fma4(acc[6],  w1.z, x4); fma4(acc[7],  w1.w, x4);
    fma4(acc[8],  w2.x, x4); fma4(acc[9],  w2.y, x4);
    fma4(acc[10], w2.z, x4); fma4(acc[11], w2.w, x4);
    fma4(acc[12], w3.x, x4); fma4(acc[13], w3.y, x4);
    fma4(acc[14], w3.z, x4); fma4(acc[15], w3.w, x4);
  }
  float* zp = Zp + ((size_t)(nc * BB + b)) * HEADS * DIM + c4 * 4;
  #pragma unroll
  for (int h = 0; h < HEADS; ++h) *(float4*)(zp + (size_t)h * DIM) = acc[h];
}

// ---------------- K5b: reduce partials (float4) ----------------
__global__ void k_zred(const float* __restrict__ Zp, float* __restrict__ Z, int nchunk) {
  size_t i = ((size_t)blockIdx.x * 256 + threadIdx.x) * 4;  // grid 512 -> 524288 floats
  const size_t STRIDE = (size_t)BB * HEADS * DIM;
  float4 s = *(const float4*)(Zp + i);
  for (int c = 1; c < nchunk; ++c) {
    float4 p = *(const float4*)(Zp + c * STRIDE + i);
    s.x += p.x; s.y += p.y; s.z += p.z; s.w += p.w;
  }
  *(float4*)(Z + i) = s;
}

// ---------------- K6: T[b,df] = Z[b,h(df),:] . Wv[df,:] ----------------
__global__ void k_ov(const float* __restrict__ Z, const float* __restrict__ Wv,
                     float* __restrict__ T) {
  int wave = threadIdx.x >> 6, lane = threadIdx.x & 63;
  int dfb = blockIdx.x;                       // grid 256
  for (int dot = wave; dot < 128; dot += 4) {
    int b = dot >> 2, dfl = dot & 3;
    int df = dfb * 4 + dfl, h = df >> 6;
    const float* wr = Wv + (size_t)df * DIM + lane * 4;
    const float* zr = Z + ((size_t)b * HEADS + h) * DIM + lane * 4;
    float acc = 0.f;
    #pragma unroll
    for (int k = 0; k < 4; ++k) {
      float4 a = *(const float4*)(wr + k * 256);
      float4 z = *(const float4*)(zr + k * 256);
      acc += a.x * z.x + a.y * z.y + a.z * z.z + a.w * z.w;
    }
    #pragma unroll
    for (int off = 32; off; off >>= 1) acc += __shfl_xor(acc, off);
    if (lane == 0) T[(size_t)b * DIM + df] = acc;
  }
}

// ---------------- K7: U = LN0(S + T + l*bv) ----------------
__global__ void k_ln0(const float* __restrict__ S, const float* __restrict__ T,
                      const float* __restrict__ lsum, const float* __restrict__ bv,
                      const float* __restrict__ g0, const float* __restrict__ b0,
                      float* __restrict__ U) {
  __shared__ float red[4];
  int b = blockIdx.x, tid = threadIdx.x, d0 = tid * 4;   // grid 32
  float4 s4 = *(const float4*)(S + d0);
  float4 t4 = *(const float4*)(T + (size_t)b * DIM + d0);
  float4 v4 = *(const float4*)(bv + d0);
  float lh = lsum[b * HEADS + (d0 >> 6)];
  float x0 = s4.x + t4.x + lh * v4.x;
  float x1 = s4.y + t4.y + lh * v4.y;
  float x2 = s4.z + t4.z + lh * v4.z;
  float x3 = s4.w + t4.w + lh * v4.w;
  float mu = block_sum256(x0 + x1 + x2 + x3, red) * (1.f / DIM);
  float e0 = x0 - mu, e1 = x1 - mu, e2 = x2 - mu, e3 = x3 - mu;
  float var = block_sum256(e0 * e0 + e1 * e1 + e2 * e2 + e3 * e3, red) * (1.f / DIM);
  float r = rsqrtf(var + LN_EPS);
  float4 g4 = *(const float4*)(g0 + d0);
  float4 bb4 = *(const float4*)(b0 + d0);
  float4 o;
  o.x = e0 * r * g4.x + bb4.x;
  o.y = e1 * r * g4.y + bb4.y;
  o.z = e2 * r * g4.z + bb4.z;
  o.w = e3 * r * g4.w + bb4.w;
  *(float4*)(U + (size_t)b * DIM + d0) = o;
}

// ---------------- K8: R = relu(U . Wo^T + bo) ----------------
__global__ void k_wo(const float* __restrict__ U, const float* __restrict__ Wo,
                     const float* __restrict__ bo, float* __restrict__ R) {
  int wave = threadIdx.x >> 6, lane = threadIdx.x & 63;
  int dfb = blockIdx.x;                       // grid 256
  for (int dot = wave; dot < 128; dot += 4) {
    int b = dot >> 2, dfl = dot & 3;
    int df = dfb * 4 + dfl;
    const float* wr = Wo + (size_t)df * DIM + lane * 4;
    const float* ur = U + (size_t)b * DIM + lane * 4;
    float acc = 0.f;
    #pragma unroll
    for (int k = 0; k < 4; ++k) {
      float4 a = *(const float4*)(wr + k * 256);
      float4 u = *(const float4*)(ur + k * 256);
      acc += a.x * u.x + a.y * u.y + a.z * u.z + a.w * u.w;
    }
    #pragma unroll
    for (int off = 32; off; off >>= 1) acc += __shfl_xor(acc, off);
    if (lane == 0) R[(size_t)b * DIM + df] = fmaxf(acc + bo[df], 0.f);
  }
}

// ---------------- K9: out = LN1(U + R) ----------------
__global__ void k_ln1(const float* __restrict__ U, const float* __restrict__ R,
                      const float* __restrict__ g1, const float* __restrict__ b1,
                      float* __restrict__ out) {
  __shared__ float red[4];
  int b = blockIdx.x, tid = threadIdx.x, d0 = tid * 4;   // grid 32
  float4 u4 = *(const float4*)(U + (size_t)b * DIM + d0);
  float4 r4 = *(const float4*)(R + (size_t)b * DIM + d0);
  float x0 = u4.x + r4.x, x1 = u4.y + r4.y, x2 = u4.z + r4.z, x3 = u4.w + r4.w;
  float mu = block_sum256(x0 + x1 + x2 + x3, red) * (1.f / DIM);
  float e0 = x0 - mu, e1 = x1 - mu, e2 = x2 - mu, e3 = x3 - mu;
  float var = block_sum256(e0 * e0 + e1 * e1 + e2 * e2 + e3 * e3, red) * (1.f / DIM);
  float r = rsqrtf(var + LN_EPS);
  float4 g4 = *(const float4*)(g1 + d0);
  float4 bb4 = *(const float4*)(b1 + d0);
  float4 o;
  o.x = e0 * r * g4.x + bb4.x;
  o.y = e1 * r * g4.y + bb4.y;
  o.z = e2 * r * g4.z + bb4.z;
  o.w = e3 * r * g4.w + bb4.w;
  *(float4*)(out + (size_t)b * DIM + d0) = o;
}

extern "C" void kernel_launch(void* const* d_in, const int* in_sizes, int n_in,
                              void* d_out, int out_size, void* d_ws, size_t ws_size,
                              hipStream_t stream) {
  (void)in_sizes; (void)n_in; (void)out_size;
  const float* X  = (const float*)d_in[0];
  const int*   mask = (const int*)d_in[1];
  const float* S  = (const float*)d_in[2];
  const float* Wq = (const float*)d_in[3];
  const float* bq = (const float*)d_in[4];
  const float* Wk = (const float*)d_in[5];
  const float* bk = (const float*)d_in[6];
  const float* Wv = (const float*)d_in[7];
  const float* bv = (const float*)d_in[8];
  const float* Wo = (const float*)d_in[9];
  const float* bo = (const float*)d_in[10];
  const float* g0 = (const float*)d_in[11];
  const float* b0 = (const float*)d_in[12];
  const float* g1 = (const float*)d_in[13];
  const float* b1 = (const float*)d_in[14];
  float* out = (float*)d_out;

  const size_t ZSTRIDE = (size_t)BB * HEADS * DIM;        // 524288 floats per chunk
  const size_t BASEF   = 1048576 + 524288 + 16384 + 16 + 512 + 65536 + 64 + 1024;
  int nchunk = 32;
  if (ws_size < (BASEF + 32 * ZSTRIDE) * 4) nchunk = 16;
  if (ws_size < (BASEF + 16 * ZSTRIDE) * 4) nchunk = 8;
  if (ws_size < (BASEF + 8  * ZSTRIDE) * 4) nchunk = 4;

  float* W    = (float*)d_ws;
  float* Zp   = W;                            // nchunk * 524288 f
  float* P    = W;                            // alias: 1,048,576 f (dead before k_z3)
  float* w    = W + (size_t)nchunk * ZSTRIDE; // 1,048,576 f, [b][slot][h]
  float* Z    = w + 1048576;                  //   524,288 f
  float* qk   = Z + 524288;                   //    16,384 f
  float* qb   = qk + 16384;                   //        16 f
  float* lsum = qb + 16;                      //       512 f
  int*   idx  = (int*)(lsum + 512);           // 65,536 ints
  int*   cnt  = idx + 65536;                  // 32 ints
  float* T    = w;                            // alias: w dead after k_z3
  float* U    = w + 32768;
  float* R    = w + 65536;

  k_index   <<<32,            256, 0, stream>>>(mask, idx, cnt);
  k_qkp     <<<64,            256, 0, stream>>>(S, Wq, bq, Wk, bk, qk, qb);
  k_scores5 <<<512,           256, 0, stream>>>(X, qk, idx, cnt, P);
  k_softmax4<<<512,           256, 0, stream>>>(P, qb, cnt, w, lsum);
  k_z3      <<<32 * nchunk,   256, 0, stream>>>(X, w, idx, cnt, Zp, nchunk);
  k_zred    <<<512,           256, 0, stream>>>(Zp, Z, nchunk);
  k_ov      <<<256,           256, 0, stream>>>(Z, Wv, T);
  k_ln0     <<<32,            256, 0, stream>>>(S, T, lsum, bv, g0, b0, U);
  k_wo      <<<256,           256, 0, stream>>>(U, Wo, bo, R);
  k_ln1     <<<32,            256, 0, stream>>>(U, R, g1, b1, out);
}

// Round 6
// 141.235 us; speedup vs baseline: 1.1348x; 1.1348x over previous
//
#include <hip/hip_runtime.h>
#include <hip/hip_bf16.h>
#include <cstdint>

#define DIM   1024
#define HEADS 16
#define BB    32
#define NN    2048
#define DH    64

constexpr float SCALE = 0.03125f;  // 1/sqrt(1024)
constexpr float LN_EPS = 1e-5f;

typedef __attribute__((ext_vector_type(8))) short short8v;
typedef __attribute__((ext_vector_type(4))) float f32x4;

__device__ __forceinline__ short f2bf(float f) {
  union { __hip_bfloat16 h; short s; } u;
  u.h = __float2bfloat16(f);
  return u.s;
}
__device__ __forceinline__ short8v pack8(float4 a, float4 b) {
  short8v v;
  v[0] = f2bf(a.x); v[1] = f2bf(a.y); v[2] = f2bf(a.z); v[3] = f2bf(a.w);
  v[4] = f2bf(b.x); v[5] = f2bf(b.y); v[6] = f2bf(b.z); v[7] = f2bf(b.w);
  return v;
}
__device__ __forceinline__ void fma4(float4& a, float s, float4 x) {
  a.x += s * x.x; a.y += s * x.y; a.z += s * x.z; a.w += s * x.w;
}

// ---------------- helpers ----------------
__device__ __forceinline__ float block_sum256(float v, volatile float* red) {
  #pragma unroll
  for (int off = 32; off; off >>= 1) v += __shfl_xor(v, off);
  __syncthreads();
  if ((threadIdx.x & 63) == 0) red[threadIdx.x >> 6] = v;
  __syncthreads();
  return red[0] + red[1] + red[2] + red[3];
}

// ---------------- K0 (merged): blocks 0-63 = qk projection (bf16 swizzled); 64-95 = index compaction ----------------
__global__ void k_front(const int* __restrict__ mask, const float* __restrict__ S,
                        const float* __restrict__ Wq, const float* __restrict__ bq,
                        const float* __restrict__ Wk, const float* __restrict__ bk,
                        short* __restrict__ qk_bf, float* __restrict__ qb,
                        int* __restrict__ idx, int* __restrict__ cnt) {
  __shared__ float qpl[DH];
  __shared__ int wsum[4];
  int tid = threadIdx.x;
  if (blockIdx.x >= 64) {
    // ---- index compaction for batch b ----
    int b = blockIdx.x - 64;
    const int* mb = mask + b * NN;
    int base = tid * 8;
    int loc[8], c = 0;
    #pragma unroll
    for (int i = 0; i < 8; ++i) { loc[i] = mb[base + i]; c += (loc[i] != 0); }
    int pre = c;
    #pragma unroll
    for (int off = 1; off < 64; off <<= 1) {
      int y = __shfl_up(pre, off);
      if ((tid & 63) >= off) pre += y;
    }
    if ((tid & 63) == 63) wsum[tid >> 6] = pre;
    __syncthreads();
    int wo = 0;
    for (int wv = 0; wv < (tid >> 6); ++wv) wo += wsum[wv];
    int pos = wo + pre - c;
    int* ib = idx + b * NN;
    #pragma unroll
    for (int i = 0; i < 8; ++i) if (loc[i]) ib[pos++] = base + i;
    if (tid == 255) cnt[b] = wo + pre;
    return;
  }
  // ---- qk projection: Qp[h,:] then qk_bf[h][c] (bf16, XOR-swizzled 8-slots), qb[h] ----
  int h = blockIdx.x >> 2, cblk = blockIdx.x & 3;
  int r = tid >> 2, j = tid & 3;               // 4 threads per Wq row
  int d = h * DH + r;
  const float* wr = Wq + (size_t)d * DIM + j * 256;
  const float* sp = S + j * 256;
  float a = 0.f;
  #pragma unroll 8
  for (int k = 0; k < 64; ++k) {
    float4 av = *(const float4*)(wr + k * 4);
    float4 sv = *(const float4*)(sp + k * 4);
    a += av.x * sv.x + av.y * sv.y + av.z * sv.z + av.w * sv.w;
  }
  a += __shfl_xor(a, 1);
  a += __shfl_xor(a, 2);
  if (j == 0) qpl[r] = a + bq[d];
  __syncthreads();
  if (cblk == 0 && tid < 64) {                 // qb[h] = Qp[h,:] . bk[h,:]
    float v = qpl[tid] * bk[h * DH + tid];
    #pragma unroll
    for (int off = 32; off; off >>= 1) v += __shfl_xor(v, off);
    if (tid == 0) qb[h] = v;
  }
  int c = cblk * 256 + tid;
  float acc = 0.f;
  #pragma unroll 8
  for (int d0 = 0; d0 < DH; ++d0)
    acc += qpl[d0] * Wk[(size_t)(h * DH + d0) * DIM + c];
  int slot = (c >> 3) ^ (h & 7);               // pre-swizzled bf16 layout
  qk_bf[h * 1024 + slot * 8 + (c & 7)] = f2bf(acc);
}

// ---------------- K3 v6: MFMA scores, 64-slot tiles, grid 512; P[b][h][slot] ----------------
__global__ __launch_bounds__(256) void k_scores6(const float* __restrict__ X,
                                                 const short* __restrict__ qk_bf,
                                                 const int* __restrict__ idx,
                                                 const int* __restrict__ cnt,
                                                 float* __restrict__ P) {
  int b  = blockIdx.x >> 4;
  int tg = blockIdx.x & 15;
  int count = cnt[b];
  int ntiles = (count + 63) >> 6;
  if (tg >= ntiles) return;
  __shared__ short qlds[HEADS * 1024];        // 32 KB, already bf16+swizzled in global
  int tid = threadIdx.x;
  {
    const short8v* qg = (const short8v*)qk_bf;
    short8v* ql = (short8v*)qlds;
    #pragma unroll
    for (int i = 0; i < 8; ++i) ql[tid + i * 256] = qg[tid + i * 256];
  }
  __syncthreads();
  int wv = tid >> 6, lane = tid & 63;
  int r16 = lane & 15, kg = lane >> 4;
  const short* qrow = qlds + r16 * 1024;
  int hx = r16 & 7;
  const int* ib = idx + b * NN;

  for (int t = tg; t < ntiles; t += 16) {
    int tilebase = t * 64 + wv * 16;
    int s0 = tilebase + r16;
    int c0 = s0 < count ? s0 : count - 1;
    int i0 = ib[c0];
    const float* x0 = X + ((size_t)b * NN + i0) * DIM + kg * 8;
    f32x4 accA = {0.f, 0.f, 0.f, 0.f}, accB = {0.f, 0.f, 0.f, 0.f};
    #pragma unroll 4
    for (int k0 = 0; k0 < DIM; k0 += 64) {
      float4 a00 = *(const float4*)(x0 + k0);
      float4 a01 = *(const float4*)(x0 + k0 + 4);
      float4 a10 = *(const float4*)(x0 + k0 + 32);
      float4 a11 = *(const float4*)(x0 + k0 + 36);
      short8v b0 = *(const short8v*)(qrow + ((((k0 >> 3) + kg) ^ hx) << 3));
      short8v b1 = *(const short8v*)(qrow + ((((k0 >> 3) + 4 + kg) ^ hx) << 3));
      accA = __builtin_amdgcn_mfma_f32_16x16x32_bf16(pack8(a00, a01), b0, accA, 0, 0, 0);
      accB = __builtin_amdgcn_mfma_f32_16x16x32_bf16(pack8(a10, a11), b1, accB, 0, 0, 0);
    }
    f32x4 acc = accA + accB;
    // D: col(=r16) is head, row(=kg*4+j) is slot within the 16
    float* pb = P + ((size_t)b * HEADS + r16) * NN;
    #pragma unroll
    for (int j = 0; j < 4; ++j) {
      int os = tilebase + kg * 4 + j;
      if (os < count) pb[os] = acc[j];
    }
  }
}

// ---------------- K4: bias + scale + softmax; P[b][h][n] in (dense), w [b][slot][h] out ----------------
__global__ void k_softmax4(const float* __restrict__ P, const float* __restrict__ qb,
                           const int* __restrict__ cnt, float* __restrict__ w,
                           float* __restrict__ lsum) {
  int b = blockIdx.x >> 4, h = blockIdx.x & 15;   // grid 512
  int tid = threadIdx.x;
  int count = cnt[b];
  const float* p0 = P + ((size_t)b * HEADS + h) * NN;
  float qbh = qb[h];
  __shared__ float red[4];
  float s[8]; int vld[8];
  float mx = -3e38f;
  #pragma unroll
  for (int i = 0; i < 8; ++i) {
    int n = tid + i * 256;
    vld[i] = n < count;
    s[i] = vld[i] ? (p0[n] + qbh) * SCALE : 0.f;
    if (vld[i]) mx = fmaxf(mx, s[i]);
  }
  #pragma unroll
  for (int off = 32; off; off >>= 1) mx = fmaxf(mx, __shfl_xor(mx, off));
  if ((tid & 63) == 0) red[tid >> 6] = mx;
  __syncthreads();
  mx = fmaxf(fmaxf(red[0], red[1]), fmaxf(red[2], red[3]));
  float sum = 0.f;
  #pragma unroll
  for (int i = 0; i < 8; ++i) {
    float e = vld[i] ? __expf(s[i] - mx) : 0.f;
    s[i] = e;
    sum += e;
  }
  #pragma unroll
  for (int off = 32; off; off >>= 1) sum += __shfl_xor(sum, off);
  __syncthreads();
  if ((tid & 63) == 0) red[tid >> 6] = sum;
  __syncthreads();
  sum = red[0] + red[1] + red[2] + red[3];
  float inv = sum > 0.f ? 1.f / sum : 0.f;
  float* wb = w + (size_t)b * NN * HEADS + h;
  #pragma unroll
  for (int i = 0; i < 8; ++i) {
    int n = tid + i * 256;
    if (vld[i]) wb[(size_t)n * HEADS] = s[i] * inv;
  }
  if (tid == 0) lsum[b * HEADS + h] = sum > 0.f ? 1.f : 0.f;
}

// ---------------- K5 v4: Z partials; c-half split for occupancy; nchunk n-chunks ----------------
__global__ __launch_bounds__(128) void k_z4(const float* __restrict__ X,
                                            const float* __restrict__ w,
                                            const int* __restrict__ idx,
                                            const int* __restrict__ cnt,
                                            float* __restrict__ Zp, int nchunk) {
  int ch = blockIdx.x & 1;
  int nc = (blockIdx.x >> 1) % nchunk;
  int b  = blockIdx.x / (2 * nchunk);
  int count = cnt[b];
  int NCc = (count + nchunk - 1) / nchunk;
  int start = nc * NCc;
  int end = start + NCc; if (end > count) end = count;
  int col = ch * 512 + threadIdx.x * 4;
  const float* Xb = X + (size_t)b * NN * DIM + col;
  const float* wp = w + ((size_t)b * NN) * HEADS;
  const int* ib = idx + b * NN;
  float4 acc[HEADS];
  #pragma unroll
  for (int h = 0; h < HEADS; ++h) acc[h] = make_float4(0.f, 0.f, 0.f, 0.f);
  #pragma unroll 4
  for (int slot = start; slot < end; ++slot) {
    int n = ib[slot];
    float4 x4 = *(const float4*)(Xb + (size_t)n * DIM);
    const float4* wn = (const float4*)(wp + (size_t)slot * HEADS);  // uniform
    float4 w0 = wn[0], w1 = wn[1], w2 = wn[2], w3 = wn[3];
    fma4(acc[0],  w0.x, x4); fma4(acc[1],  w0.y, x4);
    fma4(acc[2],  w0.z, x4); fma4(acc[3],  w0.w, x4);
    fma4(acc[4],  w1.x, x4); fma4(acc[5],  w1.y, x4);
    fma4(acc[6],  w1.z, x4); fma4(acc[7],  w1.w, x4);
    fma4(acc[8],  w2.x, x4); fma4(acc[9],  w2.y, x4);
    fma4(acc[10], w2.z, x4); fma4(acc[11], w2.w, x4);
    fma4(acc[12], w3.x, x4); fma4(acc[13], w3.y, x4);
    fma4(acc[14], w3.z, x4); fma4(acc[15], w3.w, x4);
  }
  float* zp = Zp + ((size_t)(nc * BB + b)) * HEADS * DIM + col;
  #pragma unroll
  for (int h = 0; h < HEADS; ++h) *(float4*)(zp + (size_t)h * DIM) = acc[h];
}

// ---------------- K5b: reduce partials (float4) ----------------
__global__ void k_zred(const float* __restrict__ Zp, float* __restrict__ Z, int nchunk) {
  size_t i = ((size_t)blockIdx.x * 256 + threadIdx.x) * 4;  // grid 512 -> 524288 floats
  const size_t STRIDE = (size_t)BB * HEADS * DIM;
  float4 s = *(const float4*)(Zp + i);
  for (int c = 1; c < nchunk; ++c) {
    float4 p = *(const float4*)(Zp + c * STRIDE + i);
    s.x += p.x; s.y += p.y; s.z += p.z; s.w += p.w;
  }
  *(float4*)(Z + i) = s;
}

// ---------------- K6: T[b,df] = Z[b,h(df),:] . Wv[df,:] ----------------
__global__ void k_ov(const float* __restrict__ Z, const float* __restrict__ Wv,
                     float* __restrict__ T) {
  int wave = threadIdx.x >> 6, lane = threadIdx.x & 63;
  int dfb = blockIdx.x;                       // grid 256
  for (int dot = wave; dot < 128; dot += 4) {
    int b = dot >> 2, dfl = dot & 3;
    int df = dfb * 4 + dfl, h = df >> 6;
    const float* wr = Wv + (size_t)df * DIM + lane * 4;
    const float* zr = Z + ((size_t)b * HEADS + h) * DIM + lane * 4;
    float acc = 0.f;
    #pragma unroll
    for (int k = 0; k < 4; ++k) {
      float4 a = *(const float4*)(wr + k * 256);
      float4 z = *(const float4*)(zr + k * 256);
      acc += a.x * z.x + a.y * z.y + a.z * z.z + a.w * z.w;
    }
    #pragma unroll
    for (int off = 32; off; off >>= 1) acc += __shfl_xor(acc, off);
    if (lane == 0) T[(size_t)b * DIM + df] = acc;
  }
}

// ---------------- K7: U = LN0(S + T + l*bv) ----------------
__global__ void k_ln0(const float* __restrict__ S, const float* __restrict__ T,
                      const float* __restrict__ lsum, const float* __restrict__ bv,
                      const float* __restrict__ g0, const float* __restrict__ b0,
                      float* __restrict__ U) {
  __shared__ float red[4];
  int b = blockIdx.x, tid = threadIdx.x, d0 = tid * 4;   // grid 32
  float4 s4 = *(const float4*)(S + d0);
  float4 t4 = *(const float4*)(T + (size_t)b * DIM + d0);
  float4 v4 = *(const float4*)(bv + d0);
  float lh = lsum[b * HEADS + (d0 >> 6)];
  float x0 = s4.x + t4.x + lh * v4.x;
  float x1 = s4.y + t4.y + lh * v4.y;
  float x2 = s4.z + t4.z + lh * v4.z;
  float x3 = s4.w + t4.w + lh * v4.w;
  float mu = block_sum256(x0 + x1 + x2 + x3, red) * (1.f / DIM);
  float e0 = x0 - mu, e1 = x1 - mu, e2 = x2 - mu, e3 = x3 - mu;
  float var = block_sum256(e0 * e0 + e1 * e1 + e2 * e2 + e3 * e3, red) * (1.f / DIM);
  float r = rsqrtf(var + LN_EPS);
  float4 g4 = *(const float4*)(g0 + d0);
  float4 bb4 = *(const float4*)(b0 + d0);
  float4 o;
  o.x = e0 * r * g4.x + bb4.x;
  o.y = e1 * r * g4.y + bb4.y;
  o.z = e2 * r * g4.z + bb4.z;
  o.w = e3 * r * g4.w + bb4.w;
  *(float4*)(U + (size_t)b * DIM + d0) = o;
}

// ---------------- K8: R = relu(U . Wo^T + bo) ----------------
__global__ void k_wo(const float* __restrict__ U, const float* __restrict__ Wo,
                     const float* __restrict__ bo, float* __restrict__ R) {
  int wave = threadIdx.x >> 6, lane = threadIdx.x & 63;
  int dfb = blockIdx.x;                       // grid 256
  for (int dot = wave; dot < 128; dot += 4) {
    int b = dot >> 2, dfl = dot & 3;
    int df = dfb * 4 + dfl;
    const float* wr = Wo + (size_t)df * DIM + lane * 4;
    const float* ur = U + (size_t)b * DIM + lane * 4;
    float acc = 0.f;
    #pragma unroll
    for (int k = 0; k < 4; ++k) {
      float4 a = *(const float4*)(wr + k * 256);
      float4 u = *(const float4*)(ur + k * 256);
      acc += a.x * u.x + a.y * u.y + a.z * u.z + a.w * u.w;
    }
    #pragma unroll
    for (int off = 32; off; off >>= 1) acc += __shfl_xor(acc, off);
    if (lane == 0) R[(size_t)b * DIM + df] = fmaxf(acc + bo[df], 0.f);
  }
}

// ---------------- K9: out = LN1(U + R) ----------------
__global__ void k_ln1(const float* __restrict__ U, const float* __restrict__ R,
                      const float* __restrict__ g1, const float* __restrict__ b1,
                      float* __restrict__ out) {
  __shared__ float red[4];
  int b = blockIdx.x, tid = threadIdx.x, d0 = tid * 4;   // grid 32
  float4 u4 = *(const float4*)(U + (size_t)b * DIM + d0);
  float4 r4 = *(const float4*)(R + (size_t)b * DIM + d0);
  float x0 = u4.x + r4.x, x1 = u4.y + r4.y, x2 = u4.z + r4.z, x3 = u4.w + r4.w;
  float mu = block_sum256(x0 + x1 + x2 + x3, red) * (1.f / DIM);
  float e0 = x0 - mu, e1 = x1 - mu, e2 = x2 - mu, e3 = x3 - mu;
  float var = block_sum256(e0 * e0 + e1 * e1 + e2 * e2 + e3 * e3, red) * (1.f / DIM);
  float r = rsqrtf(var + LN_EPS);
  float4 g4 = *(const float4*)(g1 + d0);
  float4 bb4 = *(const float4*)(b1 + d0);
  float4 o;
  o.x = e0 * r * g4.x + bb4.x;
  o.y = e1 * r * g4.y + bb4.y;
  o.z = e2 * r * g4.z + bb4.z;
  o.w = e3 * r * g4.w + bb4.w;
  *(float4*)(out + (size_t)b * DIM + d0) = o;
}

extern "C" void kernel_launch(void* const* d_in, const int* in_sizes, int n_in,
                              void* d_out, int out_size, void* d_ws, size_t ws_size,
                              hipStream_t stream) {
  (void)in_sizes; (void)n_in; (void)out_size;
  const float* X  = (const float*)d_in[0];
  const int*   mask = (const int*)d_in[1];
  const float* S  = (const float*)d_in[2];
  const float* Wq = (const float*)d_in[3];
  const float* bq = (const float*)d_in[4];
  const float* Wk = (const float*)d_in[5];
  const float* bk = (const float*)d_in[6];
  const float* Wv = (const float*)d_in[7];
  const float* bv = (const float*)d_in[8];
  const float* Wo = (const float*)d_in[9];
  const float* bo = (const float*)d_in[10];
  const float* g0 = (const float*)d_in[11];
  const float* b0 = (const float*)d_in[12];
  const float* g1 = (const float*)d_in[13];
  const float* b1 = (const float*)d_in[14];
  float* out = (float*)d_out;

  const size_t ZSTRIDE = (size_t)BB * HEADS * DIM;        // 524288 floats per chunk
  const size_t BASEF   = 1048576 + 524288 + 8192 + 16 + 512 + 65536 + 64 + 1024;
  int nchunk = 16;
  if (ws_size < (BASEF + 16 * ZSTRIDE) * 4) nchunk = 8;
  if (ws_size < (BASEF + 8  * ZSTRIDE) * 4) nchunk = 4;

  float* W    = (float*)d_ws;
  float* Zp   = W;                            // nchunk * 524288 f
  float* P    = W;                            // alias: 1,048,576 f (dead before k_z4)
  float* w    = W + (size_t)nchunk * ZSTRIDE; // 1,048,576 f, [b][slot][h]
  float* Z    = w + 1048576;                  //   524,288 f
  short* qkbf = (short*)(Z + 524288);         //    16,384 shorts (8192 f)
  float* qb   = Z + 524288 + 8192;            //        16 f
  float* lsum = qb + 16;                      //       512 f
  int*   idx  = (int*)(lsum + 512);           // 65,536 ints
  int*   cnt  = idx + 65536;                  // 32 ints
  float* T    = w;                            // alias: w dead after k_z4
  float* U    = w + 32768;
  float* R    = w + 65536;

  k_front   <<<96,              256, 0, stream>>>(mask, S, Wq, bq, Wk, bk, qkbf, qb, idx, cnt);
  k_scores6 <<<512,             256, 0, stream>>>(X, qkbf, idx, cnt, P);
  k_softmax4<<<512,             256, 0, stream>>>(P, qb, cnt, w, lsum);
  k_z4      <<<32 * nchunk * 2, 128, 0, stream>>>(X, w, idx, cnt, Zp, nchunk);
  k_zred    <<<512,             256, 0, stream>>>(Zp, Z, nchunk);
  k_ov      <<<256,             256, 0, stream>>>(Z, Wv, T);
  k_ln0     <<<32,              256, 0, stream>>>(S, T, lsum, bv, g0, b0, U);
  k_wo      <<<256,             256, 0, stream>>>(U, Wo, bo, R);
  k_ln1     <<<32,              256, 0, stream>>>(U, R, g1, b1, out);
}

// Round 7
// 122.390 us; speedup vs baseline: 1.3095x; 1.1540x over previous
//
#include <hip/hip_runtime.h>
#include <hip/hip_bf16.h>
#include <cstdint>

#define DIM   1024
#define HEADS 16
#define BB    32
#define NN    2048
#define DH    64

constexpr float SCALE = 0.03125f;  // 1/sqrt(1024)
constexpr float LN_EPS = 1e-5f;

typedef __attribute__((ext_vector_type(8))) short short8v;
typedef __attribute__((ext_vector_type(4))) short short4v;
typedef __attribute__((ext_vector_type(4))) float f32x4;

__device__ __forceinline__ short f2bf(float f) {
  union { __hip_bfloat16 h; short s; } u;
  u.h = __float2bfloat16(f);
  return u.s;
}
__device__ __forceinline__ float bf2f(short s) {
  union { unsigned int i; float f; } u;
  u.i = ((unsigned int)(unsigned short)s) << 16;
  return u.f;
}
__device__ __forceinline__ short8v pack8(float4 a, float4 b) {
  short8v v;
  v[0] = f2bf(a.x); v[1] = f2bf(a.y); v[2] = f2bf(a.z); v[3] = f2bf(a.w);
  v[4] = f2bf(b.x); v[5] = f2bf(b.y); v[6] = f2bf(b.z); v[7] = f2bf(b.w);
  return v;
}
__device__ __forceinline__ void fma4(float4& a, float s, float4 x) {
  a.x += s * x.x; a.y += s * x.y; a.z += s * x.z; a.w += s * x.w;
}

// ---------------- helpers ----------------
__device__ __forceinline__ float block_sum256(float v, volatile float* red) {
  #pragma unroll
  for (int off = 32; off; off >>= 1) v += __shfl_xor(v, off);
  __syncthreads();
  if ((threadIdx.x & 63) == 0) red[threadIdx.x >> 6] = v;
  __syncthreads();
  return red[0] + red[1] + red[2] + red[3];
}

// ---------------- K0 (merged): blocks 0-63 = qk projection (bf16 swizzled); 64-95 = index compaction ----------------
__global__ void k_front(const int* __restrict__ mask, const float* __restrict__ S,
                        const float* __restrict__ Wq, const float* __restrict__ bq,
                        const float* __restrict__ Wk, const float* __restrict__ bk,
                        short* __restrict__ qk_bf, float* __restrict__ qb,
                        int* __restrict__ idx, int* __restrict__ cnt) {
  __shared__ float qpl[DH];
  __shared__ int wsum[4];
  int tid = threadIdx.x;
  if (blockIdx.x >= 64) {
    int b = blockIdx.x - 64;
    const int* mb = mask + b * NN;
    int base = tid * 8;
    int loc[8], c = 0;
    #pragma unroll
    for (int i = 0; i < 8; ++i) { loc[i] = mb[base + i]; c += (loc[i] != 0); }
    int pre = c;
    #pragma unroll
    for (int off = 1; off < 64; off <<= 1) {
      int y = __shfl_up(pre, off);
      if ((tid & 63) >= off) pre += y;
    }
    if ((tid & 63) == 63) wsum[tid >> 6] = pre;
    __syncthreads();
    int wo = 0;
    for (int wv = 0; wv < (tid >> 6); ++wv) wo += wsum[wv];
    int pos = wo + pre - c;
    int* ib = idx + b * NN;
    #pragma unroll
    for (int i = 0; i < 8; ++i) if (loc[i]) ib[pos++] = base + i;
    if (tid == 255) cnt[b] = wo + pre;
    return;
  }
  int h = blockIdx.x >> 2, cblk = blockIdx.x & 3;
  int r = tid >> 2, j = tid & 3;               // 4 threads per Wq row
  int d = h * DH + r;
  const float* wr = Wq + (size_t)d * DIM + j * 256;
  const float* sp = S + j * 256;
  float a = 0.f;
  #pragma unroll 8
  for (int k = 0; k < 64; ++k) {
    float4 av = *(const float4*)(wr + k * 4);
    float4 sv = *(const float4*)(sp + k * 4);
    a += av.x * sv.x + av.y * sv.y + av.z * sv.z + av.w * sv.w;
  }
  a += __shfl_xor(a, 1);
  a += __shfl_xor(a, 2);
  if (j == 0) qpl[r] = a + bq[d];
  __syncthreads();
  if (cblk == 0 && tid < 64) {                 // qb[h] = Qp[h,:] . bk[h,:]
    float v = qpl[tid] * bk[h * DH + tid];
    #pragma unroll
    for (int off = 32; off; off >>= 1) v += __shfl_xor(v, off);
    if (tid == 0) qb[h] = v;
  }
  int c = cblk * 256 + tid;
  float acc = 0.f;
  #pragma unroll 8
  for (int d0 = 0; d0 < DH; ++d0)
    acc += qpl[d0] * Wk[(size_t)(h * DH + d0) * DIM + c];
  int slot = (c >> 3) ^ (h & 7);               // pre-swizzled bf16 layout
  qk_bf[h * 1024 + slot * 8 + (c & 7)] = f2bf(acc);
}

// ---------------- K3: MFMA scores, 64-slot tiles, grid 512; P[b][h][slot] ----------------
__global__ __launch_bounds__(256) void k_scores6(const float* __restrict__ X,
                                                 const short* __restrict__ qk_bf,
                                                 const int* __restrict__ idx,
                                                 const int* __restrict__ cnt,
                                                 float* __restrict__ P) {
  int b  = blockIdx.x >> 4;
  int tg = blockIdx.x & 15;
  int count = cnt[b];
  int ntiles = (count + 63) >> 6;
  if (tg >= ntiles) return;
  __shared__ short qlds[HEADS * 1024];        // 32 KB, already bf16+swizzled in global
  int tid = threadIdx.x;
  {
    const short8v* qg = (const short8v*)qk_bf;
    short8v* ql = (short8v*)qlds;
    #pragma unroll
    for (int i = 0; i < 8; ++i) ql[tid + i * 256] = qg[tid + i * 256];
  }
  __syncthreads();
  int wv = tid >> 6, lane = tid & 63;
  int r16 = lane & 15, kg = lane >> 4;
  const short* qrow = qlds + r16 * 1024;
  int hx = r16 & 7;
  const int* ib = idx + b * NN;

  for (int t = tg; t < ntiles; t += 16) {
    int tilebase = t * 64 + wv * 16;
    int s0 = tilebase + r16;
    int c0 = s0 < count ? s0 : count - 1;
    int i0 = ib[c0];
    const float* x0 = X + ((size_t)b * NN + i0) * DIM + kg * 8;
    f32x4 accA = {0.f, 0.f, 0.f, 0.f}, accB = {0.f, 0.f, 0.f, 0.f};
    #pragma unroll 4
    for (int k0 = 0; k0 < DIM; k0 += 64) {
      float4 a00 = *(const float4*)(x0 + k0);
      float4 a01 = *(const float4*)(x0 + k0 + 4);
      float4 a10 = *(const float4*)(x0 + k0 + 32);
      float4 a11 = *(const float4*)(x0 + k0 + 36);
      short8v b0 = *(const short8v*)(qrow + ((((k0 >> 3) + kg) ^ hx) << 3));
      short8v b1 = *(const short8v*)(qrow + ((((k0 >> 3) + 4 + kg) ^ hx) << 3));
      accA = __builtin_amdgcn_mfma_f32_16x16x32_bf16(pack8(a00, a01), b0, accA, 0, 0, 0);
      accB = __builtin_amdgcn_mfma_f32_16x16x32_bf16(pack8(a10, a11), b1, accB, 0, 0, 0);
    }
    f32x4 acc = accA + accB;
    float* pb = P + ((size_t)b * HEADS + r16) * NN;
    #pragma unroll
    for (int j = 0; j < 4; ++j) {
      int os = tilebase + kg * 4 + j;
      if (os < count) pb[os] = acc[j];
    }
  }
}

// ---------------- K4: bias + scale + softmax; P[b][h][n] in, w [b][h][slot] out (coalesced) ----------------
__global__ void k_softmax5(const float* __restrict__ P, const float* __restrict__ qb,
                           const int* __restrict__ cnt, float* __restrict__ w,
                           float* __restrict__ lsum) {
  int b = blockIdx.x >> 4, h = blockIdx.x & 15;   // grid 512
  int tid = threadIdx.x;
  int count = cnt[b];
  const float* p0 = P + ((size_t)b * HEADS + h) * NN;
  float qbh = qb[h];
  __shared__ float red[4];
  float s[8]; int vld[8];
  float mx = -3e38f;
  #pragma unroll
  for (int i = 0; i < 8; ++i) {
    int n = tid + i * 256;
    vld[i] = n < count;
    s[i] = vld[i] ? (p0[n] + qbh) * SCALE : 0.f;
    if (vld[i]) mx = fmaxf(mx, s[i]);
  }
  #pragma unroll
  for (int off = 32; off; off >>= 1) mx = fmaxf(mx, __shfl_xor(mx, off));
  if ((tid & 63) == 0) red[tid >> 6] = mx;
  __syncthreads();
  mx = fmaxf(fmaxf(red[0], red[1]), fmaxf(red[2], red[3]));
  float sum = 0.f;
  #pragma unroll
  for (int i = 0; i < 8; ++i) {
    float e = vld[i] ? __expf(s[i] - mx) : 0.f;
    s[i] = e;
    sum += e;
  }
  #pragma unroll
  for (int off = 32; off; off >>= 1) sum += __shfl_xor(sum, off);
  __syncthreads();
  if ((tid & 63) == 0) red[tid >> 6] = sum;
  __syncthreads();
  sum = red[0] + red[1] + red[2] + red[3];
  float inv = sum > 0.f ? 1.f / sum : 0.f;
  float* wb = w + ((size_t)b * HEADS + h) * NN;
  #pragma unroll
  for (int i = 0; i < 8; ++i) {
    int n = tid + i * 256;
    if (vld[i]) wb[n] = s[i] * inv;                 // contiguous stores
  }
  if (tid == 0) lsum[b * HEADS + h] = sum > 0.f ? 1.f : 0.f;
}

// ---------------- K5: Z partials (bf16 out); w[b][h][slot] via uniform scalar loads ----------------
__global__ __launch_bounds__(128) void k_z5(const float* __restrict__ X,
                                            const float* __restrict__ w,
                                            const int* __restrict__ idx,
                                            const int* __restrict__ cnt,
                                            short* __restrict__ Zp, int nchunk) {
  int ch = blockIdx.x & 1;
  int nc = (blockIdx.x >> 1) % nchunk;
  int b  = blockIdx.x / (2 * nchunk);
  int count = cnt[b];
  int NCc = (count + nchunk - 1) / nchunk;
  int start = nc * NCc;
  int end = start + NCc; if (end > count) end = count;
  int col = ch * 512 + threadIdx.x * 4;
  const float* Xb = X + (size_t)b * NN * DIM + col;
  const float* wb = w + (size_t)b * HEADS * NN;
  const int* ib = idx + b * NN;
  float4 acc[HEADS];
  #pragma unroll
  for (int h = 0; h < HEADS; ++h) acc[h] = make_float4(0.f, 0.f, 0.f, 0.f);
  #pragma unroll 2
  for (int slot = start; slot < end; ++slot) {
    int n = ib[slot];
    float4 x4 = *(const float4*)(Xb + (size_t)n * DIM);
    float wv[HEADS];
    #pragma unroll
    for (int h = 0; h < HEADS; ++h) wv[h] = wb[(size_t)h * NN + slot];  // uniform -> s_load
    #pragma unroll
    for (int h = 0; h < HEADS; ++h) fma4(acc[h], wv[h], x4);
  }
  short* zp = Zp + ((size_t)(nc * BB + b)) * HEADS * DIM + col;
  #pragma unroll
  for (int h = 0; h < HEADS; ++h) {
    short4v z4;
    z4[0] = f2bf(acc[h].x); z4[1] = f2bf(acc[h].y);
    z4[2] = f2bf(acc[h].z); z4[3] = f2bf(acc[h].w);
    *(short4v*)(zp + (size_t)h * DIM) = z4;
  }
}

// ---------------- K6: fused zred+ov: block=(b,h): sum bf16 chunks -> LDS, then 64 Wv dots ----------------
__global__ __launch_bounds__(256) void k_zov(const short* __restrict__ Zp,
                                             const float* __restrict__ Wv,
                                             float* __restrict__ T, int nchunk) {
  int b = blockIdx.x >> 4, h = blockIdx.x & 15;   // grid 512
  int tid = threadIdx.x;
  __shared__ float zlds[DIM];
  const size_t CSTRIDE = (size_t)BB * HEADS * DIM;
  const short* zrow = Zp + ((size_t)(b * HEADS + h)) * DIM + tid * 4;
  float4 zs = make_float4(0.f, 0.f, 0.f, 0.f);
  for (int nc = 0; nc < nchunk; ++nc) {
    short4v z4 = *(const short4v*)(zrow + nc * CSTRIDE);
    zs.x += bf2f(z4[0]); zs.y += bf2f(z4[1]);
    zs.z += bf2f(z4[2]); zs.w += bf2f(z4[3]);
  }
  *(float4*)(zlds + tid * 4) = zs;
  __syncthreads();
  int wv = tid >> 6, lane = tid & 63;
  float4 zr[4];
  #pragma unroll
  for (int j = 0; j < 4; ++j) zr[j] = *(const float4*)(zlds + lane * 4 + j * 256);
  for (int i = 0; i < 16; ++i) {
    int df = h * 64 + wv * 16 + i;
    const float* wr = Wv + (size_t)df * DIM + lane * 4;
    float a = 0.f;
    #pragma unroll
    for (int j = 0; j < 4; ++j) {
      float4 w4 = *(const float4*)(wr + j * 256);
      a += zr[j].x * w4.x + zr[j].y * w4.y + zr[j].z * w4.z + zr[j].w * w4.w;
    }
    #pragma unroll
    for (int off = 32; off; off >>= 1) a += __shfl_xor(a, off);
    if (lane == 0) T[(size_t)b * DIM + df] = a;
  }
}

// ---------------- K7: U = LN0(S + T + l*bv) ----------------
__global__ void k_ln0(const float* __restrict__ S, const float* __restrict__ T,
                      const float* __restrict__ lsum, const float* __restrict__ bv,
                      const float* __restrict__ g0, const float* __restrict__ b0,
                      float* __restrict__ U) {
  __shared__ float red[4];
  int b = blockIdx.x, tid = threadIdx.x, d0 = tid * 4;   // grid 32
  float4 s4 = *(const float4*)(S + d0);
  float4 t4 = *(const float4*)(T + (size_t)b * DIM + d0);
  float4 v4 = *(const float4*)(bv + d0);
  float lh = lsum[b * HEADS + (d0 >> 6)];
  float x0 = s4.x + t4.x + lh * v4.x;
  float x1 = s4.y + t4.y + lh * v4.y;
  float x2 = s4.z + t4.z + lh * v4.z;
  float x3 = s4.w + t4.w + lh * v4.w;
  float mu = block_sum256(x0 + x1 + x2 + x3, red) * (1.f / DIM);
  float e0 = x0 - mu, e1 = x1 - mu, e2 = x2 - mu, e3 = x3 - mu;
  float var = block_sum256(e0 * e0 + e1 * e1 + e2 * e2 + e3 * e3, red) * (1.f / DIM);
  float r = rsqrtf(var + LN_EPS);
  float4 g4 = *(const float4*)(g0 + d0);
  float4 bb4 = *(const float4*)(b0 + d0);
  float4 o;
  o.x = e0 * r * g4.x + bb4.x;
  o.y = e1 * r * g4.y + bb4.y;
  o.z = e2 * r * g4.z + bb4.z;
  o.w = e3 * r * g4.w + bb4.w;
  *(float4*)(U + (size_t)b * DIM + d0) = o;
}

// ---------------- K8: R = relu(U . Wo^T + bo) ----------------
__global__ void k_wo(const float* __restrict__ U, const float* __restrict__ Wo,
                     const float* __restrict__ bo, float* __restrict__ R) {
  int wave = threadIdx.x >> 6, lane = threadIdx.x & 63;
  int dfb = blockIdx.x;                       // grid 256
  for (int dot = wave; dot < 128; dot += 4) {
    int b = dot >> 2, dfl = dot & 3;
    int df = dfb * 4 + dfl;
    const float* wr = Wo + (size_t)df * DIM + lane * 4;
    const float* ur = U + (size_t)b * DIM + lane * 4;
    float acc = 0.f;
    #pragma unroll
    for (int k = 0; k < 4; ++k) {
      float4 a = *(const float4*)(wr + k * 256);
      float4 u = *(const float4*)(ur + k * 256);
      acc += a.x * u.x + a.y * u.y + a.z * u.z + a.w * u.w;
    }
    #pragma unroll
    for (int off = 32; off; off >>= 1) acc += __shfl_xor(acc, off);
    if (lane == 0) R[(size_t)b * DIM + df] = fmaxf(acc + bo[df], 0.f);
  }
}

// ---------------- K9: out = LN1(U + R) ----------------
__global__ void k_ln1(const float* __restrict__ U, const float* __restrict__ R,
                      const float* __restrict__ g1, const float* __restrict__ b1,
                      float* __restrict__ out) {
  __shared__ float red[4];
  int b = blockIdx.x, tid = threadIdx.x, d0 = tid * 4;   // grid 32
  float4 u4 = *(const float4*)(U + (size_t)b * DIM + d0);
  float4 r4 = *(const float4*)(R + (size_t)b * DIM + d0);
  float x0 = u4.x + r4.x, x1 = u4.y + r4.y, x2 = u4.z + r4.z, x3 = u4.w + r4.w;
  float mu = block_sum256(x0 + x1 + x2 + x3, red) * (1.f / DIM);
  float e0 = x0 - mu, e1 = x1 - mu, e2 = x2 - mu, e3 = x3 - mu;
  float var = block_sum256(e0 * e0 + e1 * e1 + e2 * e2 + e3 * e3, red) * (1.f / DIM);
  float r = rsqrtf(var + LN_EPS);
  float4 g4 = *(const float4*)(g1 + d0);
  float4 bb4 = *(const float4*)(b1 + d0);
  float4 o;
  o.x = e0 * r * g4.x + bb4.x;
  o.y = e1 * r * g4.y + bb4.y;
  o.z = e2 * r * g4.z + bb4.z;
  o.w = e3 * r * g4.w + bb4.w;
  *(float4*)(out + (size_t)b * DIM + d0) = o;
}

extern "C" void kernel_launch(void* const* d_in, const int* in_sizes, int n_in,
                              void* d_out, int out_size, void* d_ws, size_t ws_size,
                              hipStream_t stream) {
  (void)in_sizes; (void)n_in; (void)out_size;
  const float* X  = (const float*)d_in[0];
  const int*   mask = (const int*)d_in[1];
  const float* S  = (const float*)d_in[2];
  const float* Wq = (const float*)d_in[3];
  const float* bq = (const float*)d_in[4];
  const float* Wk = (const float*)d_in[5];
  const float* bk = (const float*)d_in[6];
  const float* Wv = (const float*)d_in[7];
  const float* bv = (const float*)d_in[8];
  const float* Wo = (const float*)d_in[9];
  const float* bo = (const float*)d_in[10];
  const float* g0 = (const float*)d_in[11];
  const float* b0 = (const float*)d_in[12];
  const float* g1 = (const float*)d_in[13];
  const float* b1 = (const float*)d_in[14];
  float* out = (float*)d_out;

  // byte budget: Zp(bf16) = nchunk*1 MB unioned with P(4 MB); then w 4 MB + small
  auto need = [](int ncq) -> size_t {
    size_t zp = (size_t)ncq * 1048576;
    size_t big = zp > 4194304 ? zp : 4194304;
    return big + 4194304 + 32768 + 64 + 2048 + 262144 + 128 + 4096;
  };
  int nchunk = 16;
  if (ws_size < need(16)) nchunk = 8;
  if (ws_size < need(8))  nchunk = 4;
  size_t zp_bytes = (size_t)nchunk * 1048576;
  size_t big = zp_bytes > 4194304 ? zp_bytes : 4194304;

  char* base  = (char*)d_ws;
  short* Zp   = (short*)base;                 // nchunk * 524288 bf16
  float* P    = (float*)base;                 // alias: 1,048,576 f (dead before k_z5)
  float* w    = (float*)(base + big);         // 1,048,576 f, [b][h][slot]
  short* qkbf = (short*)(base + big + 4194304);   // 16,384 bf16
  float* qb   = (float*)(base + big + 4194304 + 32768);
  float* lsum = qb + 16;                      // 512 f
  int*   idx  = (int*)(base + big + 4194304 + 32768 + 64 + 2048);  // 65,536 ints
  int*   cnt  = idx + 65536;                  // 32 ints
  float* T    = w;                            // alias: w dead after k_z5
  float* U    = w + 32768;
  float* R    = w + 65536;

  k_front   <<<96,              256, 0, stream>>>(mask, S, Wq, bq, Wk, bk, qkbf, qb, idx, cnt);
  k_scores6 <<<512,             256, 0, stream>>>(X, qkbf, idx, cnt, P);
  k_softmax5<<<512,             256, 0, stream>>>(P, qb, cnt, w, lsum);
  k_z5      <<<32 * nchunk * 2, 128, 0, stream>>>(X, w, idx, cnt, Zp, nchunk);
  k_zov     <<<512,             256, 0, stream>>>(Zp, Wv, T, nchunk);
  k_ln0     <<<32,              256, 0, stream>>>(S, T, lsum, bv, g0, b0, U);
  k_wo      <<<256,             256, 0, stream>>>(U, Wo, bo, R);
  k_ln1     <<<32,              256, 0, stream>>>(U, R, g1, b1, out);
}